// Round 8
// baseline (749.436 us; speedup 1.0000x reference)
//
#include <hip/hip_runtime.h>
#include <math.h>

#define NB 4096
#define IN_D 230
#define DM 256
#define NL 12
#define DST 16
#define DI 512
#define DTR 16
#define XPN 48
#define XST 516   // xcs/szs row stride (shorts)
#define HST 264   // hs row stride
#define ROWS 8    // rows per workgroup

typedef __attribute__((ext_vector_type(8))) short short8;
typedef __attribute__((ext_vector_type(4))) float floatx4;

__device__ __forceinline__ float silu_f(float x) { return x / (1.0f + expf(-x)); }
__device__ __forceinline__ float softplus_f(float x) { return (x > 20.0f) ? x : log1pf(expf(x)); }
__device__ __forceinline__ short f2bf(float x) {
    union { float f; unsigned u; } v; v.f = x;
    unsigned r = v.u + 0x7fff + ((v.u >> 16) & 1);
    return (short)(r >> 16);
}
__device__ __forceinline__ float bf2f(short s) {
    union { unsigned u; float f; } v; v.u = ((unsigned)(unsigned short)s) << 16;
    return v.f;
}

// ---------- conversion kernels (once per call) ----------

__global__ __launch_bounds__(256) void conv_x(const float* __restrict__ x, short* __restrict__ xp) {
    int idx = blockIdx.x * 256 + threadIdx.x;
    int r = idx >> 8, k = idx & 255;
    float v = (k < IN_D) ? x[(size_t)r * IN_D + k] : 0.0f;
    xp[idx] = f2bf(v);
}

// src [K x N] fp32 -> dst [Np x Kp] bf16 (dst[n][k]=src[k][n], zero-pad)
__global__ __launch_bounds__(256) void conv_wt_t(const float* __restrict__ src0, short* __restrict__ dst0,
                                                 int K, int N, int Kp, int Np) {
    const float* src = src0 + (size_t)blockIdx.z * K * N;
    short* dst = dst0 + (size_t)blockIdx.z * Np * Kp;
    __shared__ float t[64][65];
    const int k0 = blockIdx.x * 64, n0 = blockIdx.y * 64;
    const int r = threadIdx.x >> 6, c = threadIdx.x & 63;
#pragma unroll
    for (int i = 0; i < 16; i++) {
        int kk = k0 + i * 4 + r;
        int nn = n0 + c;
        float v = (kk < K && nn < N) ? src[(size_t)kk * N + nn] : 0.0f;
        t[i * 4 + r][c] = v;
    }
    __syncthreads();
#pragma unroll
    for (int i = 0; i < 16; i++) {
        int nn = n0 + i * 4 + r;
        int kk = k0 + c;
        dst[(size_t)nn * Kp + kk] = f2bf(t[c][i * 4 + r]);
    }
}

// dt_w [NL][16][512] fp32 -> dtwT [NL][512][16] fp32
__global__ __launch_bounds__(256) void conv_dtw(const float* __restrict__ src, float* __restrict__ dst) {
    int l = blockIdx.y;
    int idx = blockIdx.x * 256 + threadIdx.x;
    int d = idx >> 4, r = idx & 15;
    dst[(size_t)l * DI * DTR + idx] = src[(size_t)l * DTR * DI + r * DI + d];
}

// ---------- the whole network, fused: 512 wgs x 8 rows, 512 threads (2 blocks/CU) ----------
__global__ __launch_bounds__(512, 4) void mamba_all(
    const short* __restrict__ xpad, const short* __restrict__ WiT,
    const float* __restrict__ bi,
    const short* __restrict__ ipT, const short* __restrict__ opT,
    const short* __restrict__ xpT, const float* __restrict__ dtwT,
    const float* __restrict__ conv_w, const float* __restrict__ conv_b,
    const float* __restrict__ dt_b, const float* __restrict__ Dp,
    const float* __restrict__ Wo, const float* __restrict__ bo,
    float* __restrict__ out)
{
    __shared__ short hs[ROWS * HST];
    __shared__ short xcs[ROWS * XST];    // xc, then y in place
    __shared__ short szs[ROWS * XST];
    __shared__ float dbls[ROWS * 68];
    __shared__ float sbc[ROWS];

    const int tid = threadIdx.x;
    const int w = tid >> 6, lane = tid & 63;
    const int q = lane >> 4, m16 = lane & 15;
    const int m8 = m16 & 7;              // A rows duplicated (M=8)
    const int rb = blockIdx.x * ROWS;

    // stage 0: h = xpad @ WiT + bi   (wave w: col-frags {w, w+8})
    {
        floatx4 acc[2];
#pragma unroll
        for (int t = 0; t < 2; t++) acc[t] = (floatx4){0.f, 0.f, 0.f, 0.f};
        const short* Ap = xpad + (size_t)(rb + m8) * DM + q * 8;
#pragma unroll
        for (int kk = 0; kk < DM; kk += 32) {
            short8 a = *(const short8*)(Ap + kk);
#pragma unroll
            for (int t = 0; t < 2; t++) {
                const short* Bp = WiT + (size_t)((w + t * 8) * 16 + m16) * DM + q * 8;
                short8 bb = *(const short8*)(Bp + kk);
                acc[t] = __builtin_amdgcn_mfma_f32_16x16x32_bf16(a, bb, acc[t], 0, 0, 0);
            }
        }
        if (q < 2) {
#pragma unroll
            for (int t = 0; t < 2; t++) {
                int col = (w + t * 8) * 16 + m16;
#pragma unroll
                for (int r = 0; r < 4; r++)
                    hs[(q * 4 + r) * HST + col] = f2bf(acc[t][r] + bi[col]);
            }
        }
    }
    __syncthreads();

    for (int l = 0; l < NL; l++) {
        const short* ip = ipT + (size_t)l * 2 * DI * DM;
        const short* xp = xpT + (size_t)l * 64 * DI;
        const short* op = opT + (size_t)l * DM * DI;
        const float* dw = dtwT + (size_t)l * DI * DTR;
        const float* cw = conv_w + (size_t)l * DI * 4;
        const float* cb = conv_b + (size_t)l * DI;
        const float* db = dt_b + (size_t)l * DI;
        const float* Dv = Dp + (size_t)l * DI;

        // stage 1: xz = h @ in_projT  (wave w: 8 col-frags = cols [w*128, w*128+128))
        {
            floatx4 acc[8];
#pragma unroll
            for (int t = 0; t < 8; t++) acc[t] = (floatx4){0.f, 0.f, 0.f, 0.f};
            const short* Bp = ip + (size_t)(w * 128 + m16) * DM + q * 8;
            const short* Ar = hs + m8 * HST + q * 8;
#pragma unroll
            for (int kk = 0; kk < 8; kk++) {
                short8 a = *(const short8*)(Ar + kk * 32);
                short8 bb[8];
#pragma unroll
                for (int t = 0; t < 8; t++)
                    bb[t] = *(const short8*)(Bp + (size_t)t * 16 * DM + kk * 32);
#pragma unroll
                for (int t = 0; t < 8; t++)
                    acc[t] = __builtin_amdgcn_mfma_f32_16x16x32_bf16(a, bb[t], acc[t], 0, 0, 0);
            }
            if (q < 2) {
                if (w < 4) {
#pragma unroll
                    for (int t = 0; t < 8; t++)
#pragma unroll
                        for (int r = 0; r < 4; r++) {
                            int col = w * 128 + t * 16 + m16;
                            float v = silu_f(acc[t][r] * cw[col * 4 + 3] + cb[col]);
                            xcs[(q * 4 + r) * XST + col] = f2bf(v);
                        }
                } else {
#pragma unroll
                    for (int t = 0; t < 8; t++)
#pragma unroll
                        for (int r = 0; r < 4; r++) {
                            int col = (w - 4) * 128 + t * 16 + m16;
                            szs[(q * 4 + r) * XST + col] = f2bf(silu_f(acc[t][r]));
                        }
                }
            }
        }
        __syncthreads();

        // stage 2: dbl = xc @ x_projT  (waves 0..3, frag w, 2 accumulators)
        if (w < 4) {
            floatx4 a0 = (floatx4){0.f, 0.f, 0.f, 0.f};
            floatx4 a1 = (floatx4){0.f, 0.f, 0.f, 0.f};
            const short* Bp = xp + (size_t)(w * 16 + m16) * DI + q * 8;
            const short* Ar = xcs + m8 * XST + q * 8;
#pragma unroll
            for (int kk = 0; kk < 16; kk += 2) {
                short8 av0 = *(const short8*)(Ar + kk * 32);
                short8 bv0 = *(const short8*)(Bp + kk * 32);
                short8 av1 = *(const short8*)(Ar + kk * 32 + 32);
                short8 bv1 = *(const short8*)(Bp + kk * 32 + 32);
                a0 = __builtin_amdgcn_mfma_f32_16x16x32_bf16(av0, bv0, a0, 0, 0, 0);
                a1 = __builtin_amdgcn_mfma_f32_16x16x32_bf16(av1, bv1, a1, 0, 0, 0);
            }
            a0 = a0 + a1;
            if (q < 2) {
#pragma unroll
                for (int r = 0; r < 4; r++)
                    dbls[(q * 4 + r) * 68 + w * 16 + m16] = a0[r];
            }
        }
        __syncthreads();

        // bc[row] = dbl[row,16:32].dbl[row,32:48]  (128 threads, shuffle-reduce)
        if (tid < ROWS * 16) {
            int row = tid >> 4, s = tid & 15;
            float p = dbls[row * 68 + DTR + s] * dbls[row * 68 + DTR + DST + s];
            p += __shfl_xor(p, 1);
            p += __shfl_xor(p, 2);
            p += __shfl_xor(p, 4);
            p += __shfl_xor(p, 8);
            if (s == 0) sbc[row] = p;
        }
        __syncthreads();

        // stage 3: y = (softplus(dt)*bc + D) * xc * sz   (1 d/thread, 8 rows)
        {
            const int d3 = tid;
            float wv[DTR];
            const float* wp = dw + (size_t)d3 * DTR;
#pragma unroll
            for (int r = 0; r < DTR; r++) wv[r] = wp[r];
            const float db3 = db[d3], dv3 = Dv[d3];
#pragma unroll
            for (int i = 0; i < ROWS; i++) {
                float a = db3;
#pragma unroll
                for (int r = 0; r < DTR; r++) a += dbls[i * 68 + r] * wv[r];
                float dt = softplus_f(a);
                int off = i * XST + d3;
                float v = (dt * sbc[i] + dv3) * bf2f(xcs[off]) * bf2f(szs[off]);
                xcs[off] = f2bf(v);
            }
        }
        __syncthreads();

        // stage 4: h = y @ out_projT  (wave w: col-frags {w, w+8}, 2 accs each)
        {
            const short* Ar = xcs + m8 * XST + q * 8;
            floatx4 a0[2], a1[2];
#pragma unroll
            for (int t = 0; t < 2; t++) {
                a0[t] = (floatx4){0.f, 0.f, 0.f, 0.f};
                a1[t] = (floatx4){0.f, 0.f, 0.f, 0.f};
            }
#pragma unroll
            for (int kk = 0; kk < 16; kk += 2) {
                short8 av0 = *(const short8*)(Ar + kk * 32);
                short8 av1 = *(const short8*)(Ar + kk * 32 + 32);
#pragma unroll
                for (int t = 0; t < 2; t++) {
                    const short* Bp = op + (size_t)((w + t * 8) * 16 + m16) * DI + q * 8;
                    short8 bv0 = *(const short8*)(Bp + kk * 32);
                    short8 bv1 = *(const short8*)(Bp + kk * 32 + 32);
                    a0[t] = __builtin_amdgcn_mfma_f32_16x16x32_bf16(av0, bv0, a0[t], 0, 0, 0);
                    a1[t] = __builtin_amdgcn_mfma_f32_16x16x32_bf16(av1, bv1, a1[t], 0, 0, 0);
                }
            }
            if (q < 2) {
#pragma unroll
                for (int t = 0; t < 2; t++) {
                    floatx4 s = a0[t] + a1[t];
                    int col = (w + t * 8) * 16 + m16;
#pragma unroll
                    for (int r = 0; r < 4; r++)
                        hs[(q * 4 + r) * HST + col] = f2bf(s[r]);
                }
            }
        }
        __syncthreads();
    }

    // final: wave w reduces row w  (8 waves, 8 rows)
    {
        float s = 0.0f;
#pragma unroll
        for (int j = 0; j < 4; j++)
            s += bf2f(hs[w * HST + lane * 4 + j]) * Wo[lane * 4 + j];
#pragma unroll
        for (int off = 32; off > 0; off >>= 1) s += __shfl_down(s, off);
        if (lane == 0) out[rb + w] = s + bo[0];
    }
}

extern "C" void kernel_launch(void* const* d_in, const int* in_sizes, int n_in,
                              void* d_out, int out_size, void* d_ws, size_t ws_size,
                              hipStream_t stream)
{
    const float* x       = (const float*)d_in[0];
    const float* Wi      = (const float*)d_in[1];
    const float* bi      = (const float*)d_in[2];
    const float* in_proj = (const float*)d_in[3];
    const float* conv_w  = (const float*)d_in[4];
    const float* conv_b  = (const float*)d_in[5];
    const float* x_proj  = (const float*)d_in[6];
    const float* dt_w    = (const float*)d_in[7];
    const float* dt_b    = (const float*)d_in[8];
    // d_in[9] = A_log: dead (L==1, h0==0)
    const float* Dp      = (const float*)d_in[10];
    const float* out_pw  = (const float*)d_in[11];
    const float* Wo      = (const float*)d_in[12];
    const float* bo      = (const float*)d_in[13];

    short* ws   = (short*)d_ws;
    short* xpad = ws;                                   // 4096*256
    short* WiT  = xpad + (size_t)NB * DM;               // 256*256
    short* ipT  = WiT + (size_t)DM * DM;                // 12*1024*256
    short* opT  = ipT + (size_t)NL * 2 * DI * DM;       // 12*256*512
    short* xpT  = opT + (size_t)NL * DM * DI;           // 12*64*512
    float* dtwT = (float*)(xpT + (size_t)NL * 64 * DI); // 12*512*16 fp32

    dim3 blk(256);

    conv_x<<<dim3(NB * DM / 256), blk, 0, stream>>>(x, xpad);
    conv_wt_t<<<dim3(4, 4, 1), blk, 0, stream>>>(Wi, WiT, IN_D, DM, DM, DM);
    conv_wt_t<<<dim3(4, 16, NL), blk, 0, stream>>>(in_proj, ipT, DM, 2 * DI, DM, 2 * DI);
    conv_wt_t<<<dim3(8, 4, NL), blk, 0, stream>>>(out_pw, opT, DI, DM, DI, DM);
    conv_wt_t<<<dim3(8, 1, NL), blk, 0, stream>>>(x_proj, xpT, DI, XPN, DI, 64);
    conv_dtw<<<dim3(DI * DTR / 256, NL), blk, 0, stream>>>(dt_w, dtwT);

    mamba_all<<<dim3(NB / ROWS), dim3(512), 0, stream>>>(
        xpad, WiT, bi, ipT, opT, xpT, dtwT,
        conv_w, conv_b, dt_b, Dp, Wo, bo, (float*)d_out);
}

// Round 9
// 532.648 us; speedup vs baseline: 1.4070x; 1.4070x over previous
//
#include <hip/hip_runtime.h>
#include <hip/hip_fp8.h>
#include <math.h>

#define NB 4096
#define IN_D 230
#define DM 256
#define NL 12
#define DST 16
#define DI 512
#define DTR 16
#define XPN 48
#define XB 520    // xcs/szs row stride (bytes)
#define HB 264    // hs row stride (bytes)

typedef __attribute__((ext_vector_type(4))) float floatx4;

__device__ __forceinline__ float silu_f(float x) { return x / (1.0f + expf(-x)); }
__device__ __forceinline__ float softplus_f(float x) { return (x > 20.0f) ? x : log1pf(expf(x)); }

__device__ __forceinline__ unsigned char f2fp8(float x) {
    __hip_fp8_e4m3 t(x);
    return (unsigned char)t.__x;
}
__device__ __forceinline__ float fp82f(unsigned char b) {
    __hip_fp8_e4m3 t; t.__x = (__hip_fp8_storage_t)b;
    return (float)t;
}

// ---------- conversion kernels (once per call) ----------

// x [4096 x 230] fp32 -> xpad [4096 x 256] fp8 (zero-padded K)
__global__ __launch_bounds__(256) void conv_x(const float* __restrict__ x, unsigned char* __restrict__ xp) {
    int idx = blockIdx.x * 256 + threadIdx.x;
    int r = idx >> 8, k = idx & 255;
    float v = (k < IN_D) ? x[(size_t)r * IN_D + k] : 0.0f;
    xp[idx] = f2fp8(v);
}

// src [K x N] fp32 -> dst [Np x Kp] fp8 (dst[n][k]=src[k][n], zero-pad)
__global__ __launch_bounds__(256) void conv_wt_f8(const float* __restrict__ src0, unsigned char* __restrict__ dst0,
                                                  int K, int N, int Kp, int Np) {
    const float* src = src0 + (size_t)blockIdx.z * K * N;
    unsigned char* dst = dst0 + (size_t)blockIdx.z * Np * Kp;
    __shared__ float t[64][65];
    const int k0 = blockIdx.x * 64, n0 = blockIdx.y * 64;
    const int r = threadIdx.x >> 6, c = threadIdx.x & 63;
#pragma unroll
    for (int i = 0; i < 16; i++) {
        int kk = k0 + i * 4 + r;
        int nn = n0 + c;
        float v = (kk < K && nn < N) ? src[(size_t)kk * N + nn] : 0.0f;
        t[i * 4 + r][c] = v;
    }
    __syncthreads();
#pragma unroll
    for (int i = 0; i < 16; i++) {
        int nn = n0 + i * 4 + r;
        int kk = k0 + c;
        dst[(size_t)nn * Kp + kk] = f2fp8(t[c][i * 4 + r]);
    }
}

// dt_w [NL][16][512] fp32 -> dtwT [NL][512][16] fp32
__global__ __launch_bounds__(256) void conv_dtw(const float* __restrict__ src, float* __restrict__ dst) {
    int l = blockIdx.y;
    int idx = blockIdx.x * 256 + threadIdx.x;
    int d = idx >> 4, r = idx & 15;
    dst[(size_t)l * DI * DTR + idx] = src[(size_t)l * DTR * DI + r * DI + d];
}

// ---------- the whole network, fused: 256 wgs x 16 rows, 1024 threads, fp8 ----------
__global__ __launch_bounds__(1024) void mamba_all(
    const unsigned char* __restrict__ xpad, const unsigned char* __restrict__ WiT,
    const float* __restrict__ bi,
    const unsigned char* __restrict__ ipT, const unsigned char* __restrict__ opT,
    const unsigned char* __restrict__ xpT, const float* __restrict__ dtwT,
    const float* __restrict__ conv_w, const float* __restrict__ conv_b,
    const float* __restrict__ dt_b, const float* __restrict__ Dp,
    const float* __restrict__ Wo, const float* __restrict__ bo,
    float* __restrict__ out)
{
    __shared__ unsigned char hs[16 * HB];    // h (16 x 256) fp8
    __shared__ unsigned char xcs[16 * XB];   // xc, then y in place, fp8
    __shared__ unsigned char szs[16 * XB];   // silu(z) fp8
    __shared__ float dbls[16 * 68];
    __shared__ float sbc[16];

    const int tid = threadIdx.x;
    const int w = tid >> 6, lane = tid & 63;
    const int q = lane >> 4, m16 = lane & 15;
    const int rb = blockIdx.x * 16;

    // stage 0: h = xpad @ WiT + bi   (wave w: col-frag w of 16)
    {
        floatx4 acc = (floatx4){0.f, 0.f, 0.f, 0.f};
        const unsigned char* Ap = xpad + (size_t)(rb + m16) * DM + q * 8;
        const unsigned char* Bp = WiT + (size_t)(w * 16 + m16) * DM + q * 8;
#pragma unroll
        for (int kk = 0; kk < 8; kk++) {
            long a = *(const long*)(Ap + kk * 32);
            long b = *(const long*)(Bp + kk * 32);
            acc = __builtin_amdgcn_mfma_f32_16x16x32_fp8_fp8(a, b, acc, 0, 0, 0);
        }
        int col = w * 16 + m16;
#pragma unroll
        for (int r = 0; r < 4; r++)
            hs[(q * 4 + r) * HB + col] = f2fp8(acc[r] + bi[col]);
    }
    __syncthreads();

    for (int l = 0; l < NL; l++) {
        const unsigned char* ip = ipT + (size_t)l * 2 * DI * DM;
        const unsigned char* xp = xpT + (size_t)l * 64 * DI;
        const unsigned char* op = opT + (size_t)l * DM * DI;
        const float* dw = dtwT + (size_t)l * DI * DTR;
        const float* cw = conv_w + (size_t)l * DI * 4;
        const float* cb = conv_b + (size_t)l * DI;
        const float* db = dt_b + (size_t)l * DI;
        const float* Dv = Dp + (size_t)l * DI;

        // stage 1: xz = h @ in_projT  (wave w: 4 col-frags = 64 cols of 1024)
        {
            floatx4 acc[4];
#pragma unroll
            for (int t = 0; t < 4; t++) acc[t] = (floatx4){0.f, 0.f, 0.f, 0.f};
            const unsigned char* Bp = ip + (size_t)(w * 64 + m16) * DM + q * 8;
            const unsigned char* Ar = hs + m16 * HB + q * 8;
#pragma unroll
            for (int kk = 0; kk < 8; kk++) {
                long a = *(const long*)(Ar + kk * 32);
                long bb[4];
#pragma unroll
                for (int t = 0; t < 4; t++) bb[t] = *(const long*)(Bp + (size_t)t * 16 * DM + kk * 32);
#pragma unroll
                for (int t = 0; t < 4; t++)
                    acc[t] = __builtin_amdgcn_mfma_f32_16x16x32_fp8_fp8(a, bb[t], acc[t], 0, 0, 0);
            }
            if (w < 8) {
#pragma unroll
                for (int t = 0; t < 4; t++)
#pragma unroll
                    for (int r = 0; r < 4; r++) {
                        int col = w * 64 + t * 16 + m16;
                        float v = silu_f(acc[t][r] * cw[col * 4 + 3] + cb[col]);
                        xcs[(q * 4 + r) * XB + col] = f2fp8(v);
                    }
            } else {
#pragma unroll
                for (int t = 0; t < 4; t++)
#pragma unroll
                    for (int r = 0; r < 4; r++) {
                        int col = (w - 8) * 64 + t * 16 + m16;
                        szs[(q * 4 + r) * XB + col] = f2fp8(silu_f(acc[t][r]));
                    }
            }
        }
        __syncthreads();

        // stage 2: dbl = xc @ x_projT  (waves 0..3, frag w, 2 accumulators)
        if (w < 4) {
            floatx4 a0 = (floatx4){0.f, 0.f, 0.f, 0.f};
            floatx4 a1 = (floatx4){0.f, 0.f, 0.f, 0.f};
            const unsigned char* Bp = xp + (size_t)(w * 16 + m16) * DI + q * 8;
            const unsigned char* Ar = xcs + m16 * XB + q * 8;
#pragma unroll
            for (int kk = 0; kk < 16; kk += 2) {
                long av0 = *(const long*)(Ar + kk * 32);
                long bv0 = *(const long*)(Bp + kk * 32);
                long av1 = *(const long*)(Ar + kk * 32 + 32);
                long bv1 = *(const long*)(Bp + kk * 32 + 32);
                a0 = __builtin_amdgcn_mfma_f32_16x16x32_fp8_fp8(av0, bv0, a0, 0, 0, 0);
                a1 = __builtin_amdgcn_mfma_f32_16x16x32_fp8_fp8(av1, bv1, a1, 0, 0, 0);
            }
            a0 = a0 + a1;
#pragma unroll
            for (int r = 0; r < 4; r++)
                dbls[(q * 4 + r) * 68 + w * 16 + m16] = a0[r];
        }
        __syncthreads();

        // bc[row] = dbl[row,16:32].dbl[row,32:48]
        if (tid < 256) {
            int row = tid >> 4, s = tid & 15;
            float p = dbls[row * 68 + DTR + s] * dbls[row * 68 + DTR + DST + s];
            p += __shfl_xor(p, 1);
            p += __shfl_xor(p, 2);
            p += __shfl_xor(p, 4);
            p += __shfl_xor(p, 8);
            if (s == 0) sbc[row] = p;
        }
        __syncthreads();

        // stage 3: y = (softplus(dt)*bc + D) * xc * sz   (1 d/thread, 8 rows)
        {
            const int d3 = tid & 511;
            const int rh = (tid >> 9) * 8;
            float wv[DTR];
            const float* wp = dw + (size_t)d3 * DTR;
#pragma unroll
            for (int r = 0; r < DTR; r++) wv[r] = wp[r];
            const float db3 = db[d3], dv3 = Dv[d3];
#pragma unroll
            for (int i = 0; i < 8; i++) {
                int row = rh + i;
                float a = db3;
#pragma unroll
                for (int r = 0; r < DTR; r++) a += dbls[row * 68 + r] * wv[r];
                float dt = softplus_f(a);
                int off = row * XB + d3;
                float v = (dt * sbc[row] + dv3) * fp82f(xcs[off]) * fp82f(szs[off]);
                xcs[off] = f2fp8(v);
            }
        }
        __syncthreads();

        // stage 4: h = y @ out_projT  (wave w: col-frag w of 16, 2 accs)
        {
            floatx4 a0 = (floatx4){0.f, 0.f, 0.f, 0.f};
            floatx4 a1 = (floatx4){0.f, 0.f, 0.f, 0.f};
            const unsigned char* Bp = op + (size_t)(w * 16 + m16) * DI + q * 8;
            const unsigned char* Ar = xcs + m16 * XB + q * 8;
#pragma unroll
            for (int kk = 0; kk < 16; kk += 2) {
                long av0 = *(const long*)(Ar + kk * 32);
                long bv0 = *(const long*)(Bp + kk * 32);
                long av1 = *(const long*)(Ar + kk * 32 + 32);
                long bv1 = *(const long*)(Bp + kk * 32 + 32);
                a0 = __builtin_amdgcn_mfma_f32_16x16x32_fp8_fp8(av0, bv0, a0, 0, 0, 0);
                a1 = __builtin_amdgcn_mfma_f32_16x16x32_fp8_fp8(av1, bv1, a1, 0, 0, 0);
            }
            a0 = a0 + a1;
            int col = w * 16 + m16;
#pragma unroll
            for (int r = 0; r < 4; r++)
                hs[(q * 4 + r) * HB + col] = f2fp8(a0[r]);
        }
        __syncthreads();
    }

    // final: wave w reduces row w
    {
        float s = 0.0f;
#pragma unroll
        for (int j = 0; j < 4; j++)
            s += fp82f(hs[w * HB + lane * 4 + j]) * Wo[lane * 4 + j];
#pragma unroll
        for (int off = 32; off > 0; off >>= 1) s += __shfl_down(s, off);
        if (lane == 0) out[rb + w] = s + bo[0];
    }
}

extern "C" void kernel_launch(void* const* d_in, const int* in_sizes, int n_in,
                              void* d_out, int out_size, void* d_ws, size_t ws_size,
                              hipStream_t stream)
{
    const float* x       = (const float*)d_in[0];
    const float* Wi      = (const float*)d_in[1];
    const float* bi      = (const float*)d_in[2];
    const float* in_proj = (const float*)d_in[3];
    const float* conv_w  = (const float*)d_in[4];
    const float* conv_b  = (const float*)d_in[5];
    const float* x_proj  = (const float*)d_in[6];
    const float* dt_w    = (const float*)d_in[7];
    const float* dt_b    = (const float*)d_in[8];
    // d_in[9] = A_log: dead (L==1, h0==0)
    const float* Dp      = (const float*)d_in[10];
    const float* out_pw  = (const float*)d_in[11];
    const float* Wo      = (const float*)d_in[12];
    const float* bo      = (const float*)d_in[13];

    unsigned char* ws = (unsigned char*)d_ws;
    unsigned char* xpad = ws;                              // 4096*256
    unsigned char* WiT  = xpad + (size_t)NB * DM;          // 256*256
    unsigned char* ipT  = WiT + (size_t)DM * DM;           // 12*1024*256
    unsigned char* opT  = ipT + (size_t)NL * 2 * DI * DM;  // 12*256*512
    unsigned char* xpT  = opT + (size_t)NL * DM * DI;      // 12*64*512
    float* dtwT = (float*)(xpT + (size_t)NL * 64 * DI);    // 12*512*16 fp32

    dim3 blk(256);

    conv_x<<<dim3(NB * DM / 256), blk, 0, stream>>>(x, xpad);
    conv_wt_f8<<<dim3(4, 4, 1), blk, 0, stream>>>(Wi, WiT, IN_D, DM, DM, DM);
    conv_wt_f8<<<dim3(4, 16, NL), blk, 0, stream>>>(in_proj, ipT, DM, 2 * DI, DM, 2 * DI);
    conv_wt_f8<<<dim3(8, 4, NL), blk, 0, stream>>>(out_pw, opT, DI, DM, DI, DM);
    conv_wt_f8<<<dim3(8, 1, NL), blk, 0, stream>>>(x_proj, xpT, DI, XPN, DI, 64);
    conv_dtw<<<dim3(DI * DTR / 256, NL), blk, 0, stream>>>(dt_w, dtwT);

    mamba_all<<<dim3(NB / 16), dim3(1024), 0, stream>>>(
        xpad, WiT, bi, ipT, opT, xpT, dtwT,
        conv_w, conv_b, dt_b, Dp, Wo, bo, (float*)d_out);
}

// Round 10
// 329.433 us; speedup vs baseline: 2.2749x; 1.6169x over previous
//
#include <hip/hip_runtime.h>
#include <hip/hip_fp8.h>
#include <math.h>

#define NB 4096
#define IN_D 230
#define DM 256
#define NL 12
#define DST 16
#define DI 512
#define DTR 16
#define XPN 48
#define XB 520    // xcs/szs row stride (bytes)
#define HB 264    // hs row stride (bytes)

typedef __attribute__((ext_vector_type(4))) float floatx4;
typedef __attribute__((ext_vector_type(2))) long long2v;

__device__ __forceinline__ float silu_f(float x) { return x / (1.0f + expf(-x)); }
__device__ __forceinline__ float softplus_f(float x) { return (x > 20.0f) ? x : log1pf(expf(x)); }

__device__ __forceinline__ unsigned char f2fp8(float x) {
    __hip_fp8_e4m3 t(x);
    return (unsigned char)t.__x;
}
__device__ __forceinline__ float fp82f(unsigned char b) {
    __hip_fp8_e4m3 t; t.__x = (__hip_fp8_storage_t)b;
    return (float)t;
}

// ---------- conversion kernels (once per call) ----------

// x [4096 x 230] fp32 -> xpad [4096 x 256] fp8 (zero-padded K, row-major)
__global__ __launch_bounds__(256) void conv_x(const float* __restrict__ x, unsigned char* __restrict__ xp) {
    int idx = blockIdx.x * 256 + threadIdx.x;
    int r = idx >> 8, k = idx & 255;
    float v = (k < IN_D) ? x[(size_t)r * IN_D + k] : 0.0f;
    xp[idx] = f2fp8(v);
}

// src [K x N] fp32 -> dst packed fp8 fragment-major:
// chunk = cb*(Kp/64)+g ; dst[chunk*1024 + lane*16 + sub*8 + byte] = W^T fragment byte
// where lane=q*16+m16, n=cb*16+m16, k=g*64+sub*32+q*8+byte.
// One thread per dst byte; writes perfectly coalesced.
__global__ __launch_bounds__(256) void conv_wt_pack(const float* __restrict__ src0, unsigned char* __restrict__ dst0,
                                                    int K, int N, int Kp, int Np) {
    const float* src = src0 + (size_t)blockIdx.y * K * N;
    unsigned char* dst = dst0 + (size_t)blockIdx.y * Np * Kp;
    int idx = blockIdx.x * 256 + threadIdx.x;             // over Np*Kp
    int chunk = idx >> 10;
    int r = idx & 1023;
    int lane = r >> 4, r16 = r & 15;
    int sub = r16 >> 3, byt = r16 & 7;
    int q = lane >> 4, m16 = lane & 15;
    int ngroups = Kp >> 6;
    int cb = chunk / ngroups, g = chunk - cb * ngroups;
    int n = cb * 16 + m16;
    int k = g * 64 + sub * 32 + q * 8 + byt;
    float v = (k < K && n < N) ? src[(size_t)k * N + n] : 0.0f;
    dst[idx] = f2fp8(v);
}

// dt_w [NL][16][512] fp32 -> dtwT [NL][512][16] fp32
__global__ __launch_bounds__(256) void conv_dtw(const float* __restrict__ src, float* __restrict__ dst) {
    int l = blockIdx.y;
    int idx = blockIdx.x * 256 + threadIdx.x;
    int d = idx >> 4, r = idx & 15;
    dst[(size_t)l * DI * DTR + idx] = src[(size_t)l * DTR * DI + r * DI + d];
}

// ---------- the whole network, fused: 256 wgs x 16 rows, 1024 threads, fp8, packed weights ----------
__global__ __launch_bounds__(1024) void mamba_all(
    const unsigned char* __restrict__ xpad, const unsigned char* __restrict__ WiT,
    const float* __restrict__ bi,
    const unsigned char* __restrict__ ipT, const unsigned char* __restrict__ opT,
    const unsigned char* __restrict__ xpT, const float* __restrict__ dtwT,
    const float* __restrict__ conv_w, const float* __restrict__ conv_b,
    const float* __restrict__ dt_b, const float* __restrict__ Dp,
    const float* __restrict__ Wo, const float* __restrict__ bo,
    float* __restrict__ out)
{
    __shared__ unsigned char hs[16 * HB];    // h (16 x 256) fp8
    __shared__ unsigned char xcs[16 * XB];   // xc, then y in place, fp8
    __shared__ unsigned char szs[16 * XB];   // silu(z) fp8
    __shared__ float dbls[16 * 68];
    __shared__ float sbc[16];

    const int tid = threadIdx.x;
    const int w = tid >> 6, lane = tid & 63;
    const int q = lane >> 4, m16 = lane & 15;
    const int rb = blockIdx.x * 16;

    // stage 0: h = xpad @ Wi + bi   (wave w: col-blk w; Wi packed, Kp=256 -> 4 groups)
    {
        floatx4 a0 = (floatx4){0.f, 0.f, 0.f, 0.f};
        floatx4 a1 = (floatx4){0.f, 0.f, 0.f, 0.f};
        const unsigned char* Ap = xpad + (size_t)(rb + m16) * DM + q * 8;
        const unsigned char* Bp = WiT + (size_t)(w * 4) * 1024 + lane * 16;
#pragma unroll
        for (int g = 0; g < 4; g++) {
            long2v b = *(const long2v*)(Bp + g * 1024);
            long av0 = *(const long*)(Ap + (g * 2) * 32);
            long av1 = *(const long*)(Ap + (g * 2 + 1) * 32);
            a0 = __builtin_amdgcn_mfma_f32_16x16x32_fp8_fp8(av0, b.x, a0, 0, 0, 0);
            a1 = __builtin_amdgcn_mfma_f32_16x16x32_fp8_fp8(av1, b.y, a1, 0, 0, 0);
        }
        a0 = a0 + a1;
        int col = w * 16 + m16;
#pragma unroll
        for (int r = 0; r < 4; r++)
            hs[(q * 4 + r) * HB + col] = f2fp8(a0[r] + bi[col]);
    }
    __syncthreads();

    for (int l = 0; l < NL; l++) {
        const unsigned char* ip = ipT + (size_t)l * 2 * DI * DM;
        const unsigned char* xp = xpT + (size_t)l * 64 * DI;
        const unsigned char* op = opT + (size_t)l * DM * DI;
        const float* dw = dtwT + (size_t)l * DI * DTR;
        const float* cw = conv_w + (size_t)l * DI * 4;
        const float* cb = conv_b + (size_t)l * DI;
        const float* db = dt_b + (size_t)l * DI;
        const float* Dv = Dp + (size_t)l * DI;

        // stage 1: xz = h @ in_proj  (wave w: col-blks w*4..w*4+3; Kp=256 -> 4 groups)
        {
            floatx4 acc[4];
#pragma unroll
            for (int t = 0; t < 4; t++) acc[t] = (floatx4){0.f, 0.f, 0.f, 0.f};
            const unsigned char* Bp = ip + (size_t)(w * 16) * 1024 + lane * 16;
            const unsigned char* Ar = hs + m16 * HB + q * 8;
#pragma unroll
            for (int g = 0; g < 4; g++) {
                long a0 = *(const long*)(Ar + (g * 2) * 32);
                long a1 = *(const long*)(Ar + (g * 2 + 1) * 32);
                long2v b[4];
#pragma unroll
                for (int t = 0; t < 4; t++)
                    b[t] = *(const long2v*)(Bp + (t * 4 + g) * 1024);
#pragma unroll
                for (int t = 0; t < 4; t++)
                    acc[t] = __builtin_amdgcn_mfma_f32_16x16x32_fp8_fp8(a0, b[t].x, acc[t], 0, 0, 0);
#pragma unroll
                for (int t = 0; t < 4; t++)
                    acc[t] = __builtin_amdgcn_mfma_f32_16x16x32_fp8_fp8(a1, b[t].y, acc[t], 0, 0, 0);
            }
            if (w < 8) {
#pragma unroll
                for (int t = 0; t < 4; t++)
#pragma unroll
                    for (int r = 0; r < 4; r++) {
                        int col = w * 64 + t * 16 + m16;
                        float v = silu_f(acc[t][r] * cw[col * 4 + 3] + cb[col]);
                        xcs[(q * 4 + r) * XB + col] = f2fp8(v);
                    }
            } else {
#pragma unroll
                for (int t = 0; t < 4; t++)
#pragma unroll
                    for (int r = 0; r < 4; r++) {
                        int col = (w - 8) * 64 + t * 16 + m16;
                        szs[(q * 4 + r) * XB + col] = f2fp8(silu_f(acc[t][r]));
                    }
            }
        }
        __syncthreads();

        // stage 2: dbl = xc @ x_proj  (waves 0..3: col-blk w; Kp=512 -> 8 groups)
        if (w < 4) {
            floatx4 a0 = (floatx4){0.f, 0.f, 0.f, 0.f};
            floatx4 a1 = (floatx4){0.f, 0.f, 0.f, 0.f};
            const unsigned char* Bp = xp + (size_t)(w * 8) * 1024 + lane * 16;
            const unsigned char* Ar = xcs + m16 * XB + q * 8;
#pragma unroll
            for (int g = 0; g < 8; g++) {
                long2v b = *(const long2v*)(Bp + g * 1024);
                long av0 = *(const long*)(Ar + (g * 2) * 32);
                long av1 = *(const long*)(Ar + (g * 2 + 1) * 32);
                a0 = __builtin_amdgcn_mfma_f32_16x16x32_fp8_fp8(av0, b.x, a0, 0, 0, 0);
                a1 = __builtin_amdgcn_mfma_f32_16x16x32_fp8_fp8(av1, b.y, a1, 0, 0, 0);
            }
            a0 = a0 + a1;
#pragma unroll
            for (int r = 0; r < 4; r++)
                dbls[(q * 4 + r) * 68 + w * 16 + m16] = a0[r];
        }
        __syncthreads();

        // bc[row] = dbl[row,16:32].dbl[row,32:48]
        if (tid < 256) {
            int row = tid >> 4, s = tid & 15;
            float p = dbls[row * 68 + DTR + s] * dbls[row * 68 + DTR + DST + s];
            p += __shfl_xor(p, 1);
            p += __shfl_xor(p, 2);
            p += __shfl_xor(p, 4);
            p += __shfl_xor(p, 8);
            if (s == 0) sbc[row] = p;
        }
        __syncthreads();

        // stage 3: y = (softplus(dt)*bc + D) * xc * sz   (1 d/thread, 8 rows)
        {
            const int d3 = tid & 511;
            const int rh = (tid >> 9) * 8;
            float wv[DTR];
            const float* wp = dw + (size_t)d3 * DTR;
#pragma unroll
            for (int r = 0; r < DTR; r++) wv[r] = wp[r];
            const float db3 = db[d3], dv3 = Dv[d3];
#pragma unroll
            for (int i = 0; i < 8; i++) {
                int row = rh + i;
                float a = db3;
#pragma unroll
                for (int r = 0; r < DTR; r++) a += dbls[row * 68 + r] * wv[r];
                float dt = softplus_f(a);
                int off = row * XB + d3;
                float v = (dt * sbc[row] + dv3) * fp82f(xcs[off]) * fp82f(szs[off]);
                xcs[off] = f2fp8(v);
            }
        }
        __syncthreads();

        // stage 4: h = y @ out_proj  (wave w: col-blk w; Kp=512 -> 8 groups)
        {
            floatx4 a0 = (floatx4){0.f, 0.f, 0.f, 0.f};
            floatx4 a1 = (floatx4){0.f, 0.f, 0.f, 0.f};
            const unsigned char* Bp = op + (size_t)(w * 8) * 1024 + lane * 16;
            const unsigned char* Ar = xcs + m16 * XB + q * 8;
#pragma unroll
            for (int g = 0; g < 8; g++) {
                long2v b = *(const long2v*)(Bp + g * 1024);
                long av0 = *(const long*)(Ar + (g * 2) * 32);
                long av1 = *(const long*)(Ar + (g * 2 + 1) * 32);
                a0 = __builtin_amdgcn_mfma_f32_16x16x32_fp8_fp8(av0, b.x, a0, 0, 0, 0);
                a1 = __builtin_amdgcn_mfma_f32_16x16x32_fp8_fp8(av1, b.y, a1, 0, 0, 0);
            }
            a0 = a0 + a1;
            int col = w * 16 + m16;
#pragma unroll
            for (int r = 0; r < 4; r++)
                hs[(q * 4 + r) * HB + col] = f2fp8(a0[r]);
        }
        __syncthreads();
    }

    // final: wave w reduces row w
    {
        float s = 0.0f;
#pragma unroll
        for (int j = 0; j < 4; j++)
            s += fp82f(hs[w * HB + lane * 4 + j]) * Wo[lane * 4 + j];
#pragma unroll
        for (int off = 32; off > 0; off >>= 1) s += __shfl_down(s, off);
        if (lane == 0) out[rb + w] = s + bo[0];
    }
}

extern "C" void kernel_launch(void* const* d_in, const int* in_sizes, int n_in,
                              void* d_out, int out_size, void* d_ws, size_t ws_size,
                              hipStream_t stream)
{
    const float* x       = (const float*)d_in[0];
    const float* Wi      = (const float*)d_in[1];
    const float* bi      = (const float*)d_in[2];
    const float* in_proj = (const float*)d_in[3];
    const float* conv_w  = (const float*)d_in[4];
    const float* conv_b  = (const float*)d_in[5];
    const float* x_proj  = (const float*)d_in[6];
    const float* dt_w    = (const float*)d_in[7];
    const float* dt_b    = (const float*)d_in[8];
    // d_in[9] = A_log: dead (L==1, h0==0)
    const float* Dp      = (const float*)d_in[10];
    const float* out_pw  = (const float*)d_in[11];
    const float* Wo      = (const float*)d_in[12];
    const float* bo      = (const float*)d_in[13];

    unsigned char* ws = (unsigned char*)d_ws;
    unsigned char* xpad = ws;                              // 4096*256
    unsigned char* WiT  = xpad + (size_t)NB * DM;          // 256*256
    unsigned char* ipT  = WiT + (size_t)DM * DM;           // 12*1024*256
    unsigned char* opT  = ipT + (size_t)NL * 2 * DI * DM;  // 12*256*512
    unsigned char* xpT  = opT + (size_t)NL * DM * DI;      // 12*64*512
    float* dtwT = (float*)(xpT + (size_t)NL * 64 * DI);    // 12*512*16 fp32

    dim3 blk(256);

    conv_x<<<dim3(NB * DM / 256), blk, 0, stream>>>(x, xpad);
    conv_wt_pack<<<dim3(DM * DM / 256, 1), blk, 0, stream>>>(Wi, WiT, IN_D, DM, DM, DM);
    conv_wt_pack<<<dim3(2 * DI * DM / 256, NL), blk, 0, stream>>>(in_proj, ipT, DM, 2 * DI, DM, 2 * DI);
    conv_wt_pack<<<dim3(DM * DI / 256, NL), blk, 0, stream>>>(out_pw, opT, DI, DM, DI, DM);
    conv_wt_pack<<<dim3(64 * DI / 256, NL), blk, 0, stream>>>(x_proj, xpT, DI, XPN, DI, 64);
    conv_dtw<<<dim3(DI * DTR / 256, NL), blk, 0, stream>>>(dt_w, dtwT);

    mamba_all<<<dim3(NB / 16), dim3(1024), 0, stream>>>(
        xpad, WiT, bi, ipT, opT, xpT, dtwT,
        conv_w, conv_b, dt_b, Dp, Wo, bo, (float*)d_out);
}

// Round 11
// 220.093 us; speedup vs baseline: 3.4051x; 1.4968x over previous
//
#include <hip/hip_runtime.h>
#include <hip/hip_fp8.h>
#include <math.h>

#define NB 4096
#define IN_D 230
#define DM 256
#define NL 12
#define DST 16
#define DI 512
#define DTR 16
#define XPN 48
#define XB 520    // xcs/szs row stride (bytes)
#define HB 264    // hs row stride (bytes)

typedef __attribute__((ext_vector_type(4))) float floatx4;
typedef __attribute__((ext_vector_type(2))) long long2v;

// fast device math (range-reduced exactness unnecessary: values are tiny)
__device__ __forceinline__ float silu_f(float x) {
    return x * __builtin_amdgcn_rcpf(1.0f + __expf(-x));
}
__device__ __forceinline__ float softplus_f(float x) {
    return (x > 20.0f) ? x : __logf(1.0f + __expf(x));
}

// HW fp8 e4m3 converts (gfx950 = OCP), guarded fallback
__device__ __forceinline__ unsigned char f2fp8(float x) {
#if __has_builtin(__builtin_amdgcn_cvt_pk_fp8_f32)
    return (unsigned char)(__builtin_amdgcn_cvt_pk_fp8_f32(x, x, 0, false) & 0xff);
#else
    __hip_fp8_e4m3 t(x); return (unsigned char)t.__x;
#endif
}
__device__ __forceinline__ float fp82f(unsigned char b) {
#if __has_builtin(__builtin_amdgcn_cvt_f32_fp8)
    return __builtin_amdgcn_cvt_f32_fp8((int)b, 0);
#else
    __hip_fp8_e4m3 t; t.__x = (__hip_fp8_storage_t)b; return (float)t;
#endif
}

// ---------- conversion kernels (once per call) ----------

// x [4096 x 230] fp32 -> xpad [4096 x 256] fp8 (zero-padded K, row-major)
__global__ __launch_bounds__(256) void conv_x(const float* __restrict__ x, unsigned char* __restrict__ xp) {
    int idx = blockIdx.x * 256 + threadIdx.x;
    int r = idx >> 8, k = idx & 255;
    float v = (k < IN_D) ? x[(size_t)r * IN_D + k] : 0.0f;
    xp[idx] = f2fp8(v);
}

// src [K x N] fp32 -> dst packed fp8 fragment-major (1KB per 16col x 64K chunk)
__global__ __launch_bounds__(256) void conv_wt_pack(const float* __restrict__ src0, unsigned char* __restrict__ dst0,
                                                    int K, int N, int Kp, int Np) {
    const float* src = src0 + (size_t)blockIdx.y * K * N;
    unsigned char* dst = dst0 + (size_t)blockIdx.y * Np * Kp;
    int idx = blockIdx.x * 256 + threadIdx.x;             // over Np*Kp
    int chunk = idx >> 10;
    int r = idx & 1023;
    int lane = r >> 4, r16 = r & 15;
    int sub = r16 >> 3, byt = r16 & 7;
    int q = lane >> 4, m16 = lane & 15;
    int ngroups = Kp >> 6;
    int cb = chunk / ngroups, g = chunk - cb * ngroups;
    int n = cb * 16 + m16;
    int k = g * 64 + sub * 32 + q * 8 + byt;
    float v = (k < K && n < N) ? src[(size_t)k * N + n] : 0.0f;
    dst[idx] = f2fp8(v);
}

// dt_w [NL][16][512] fp32 -> packed fp8 B-fragments, K=16 padded to 32:
// dst[l][chunk*512 + lane*8 + byte], col=chunk*16+(lane&15), k=(lane>>4)*8+byte
__global__ __launch_bounds__(256) void conv_dtw_pack(const float* __restrict__ src, unsigned char* __restrict__ dst) {
    int l = blockIdx.y;
    int idx = blockIdx.x * 256 + threadIdx.x;             // over 32*512 = 16384
    int chunk = idx >> 9;
    int r = idx & 511;
    int lane = r >> 3, byt = r & 7;
    int q = lane >> 4, m16 = lane & 15;
    int col = chunk * 16 + m16;
    int k = q * 8 + byt;
    float v = (k < DTR) ? src[(size_t)l * DTR * DI + (size_t)k * DI + col] : 0.0f;
    dst[(size_t)l * 16384 + idx] = f2fp8(v);
}

// ---------- the whole network, fused: 256 wgs x 16 rows, 1024 threads, fp8, packed weights ----------
__global__ __launch_bounds__(1024) void mamba_all(
    const unsigned char* __restrict__ xpad, const unsigned char* __restrict__ WiT,
    const float* __restrict__ bi,
    const unsigned char* __restrict__ ipT, const unsigned char* __restrict__ opT,
    const unsigned char* __restrict__ xpT, const unsigned char* __restrict__ dtwP,
    const float* __restrict__ conv_w, const float* __restrict__ conv_b,
    const float* __restrict__ dt_b, const float* __restrict__ Dp,
    const float* __restrict__ Wo, const float* __restrict__ bo,
    float* __restrict__ out)
{
    __shared__ unsigned char hs[16 * HB];    // h (16 x 256) fp8
    __shared__ unsigned char xcs[16 * XB];   // xc, then y in place, fp8
    __shared__ unsigned char szs[16 * XB];   // silu(z) fp8
    __shared__ float dbls[16 * 68];
    __shared__ float sbc[16];

    const int tid = threadIdx.x;
    const int w = tid >> 6, lane = tid & 63;
    const int q = lane >> 4, m16 = lane & 15;
    const int rb = blockIdx.x * 16;

    // stage 0: h = xpad @ Wi + bi   (wave w: col-blk w; Wi packed, Kp=256 -> 4 groups)
    {
        floatx4 a0 = (floatx4){0.f, 0.f, 0.f, 0.f};
        floatx4 a1 = (floatx4){0.f, 0.f, 0.f, 0.f};
        const unsigned char* Ap = xpad + (size_t)(rb + m16) * DM + q * 8;
        const unsigned char* Bp = WiT + (size_t)(w * 4) * 1024 + lane * 16;
#pragma unroll
        for (int g = 0; g < 4; g++) {
            long2v b = *(const long2v*)(Bp + g * 1024);
            long av0 = *(const long*)(Ap + (g * 2) * 32);
            long av1 = *(const long*)(Ap + (g * 2 + 1) * 32);
            a0 = __builtin_amdgcn_mfma_f32_16x16x32_fp8_fp8(av0, b.x, a0, 0, 0, 0);
            a1 = __builtin_amdgcn_mfma_f32_16x16x32_fp8_fp8(av1, b.y, a1, 0, 0, 0);
        }
        a0 = a0 + a1;
        int col = w * 16 + m16;
#pragma unroll
        for (int r = 0; r < 4; r++)
            hs[(q * 4 + r) * HB + col] = f2fp8(a0[r] + bi[col]);
    }
    __syncthreads();

    for (int l = 0; l < NL; l++) {
        const unsigned char* ip = ipT + (size_t)l * 2 * DI * DM;
        const unsigned char* xp = xpT + (size_t)l * 64 * DI;
        const unsigned char* op = opT + (size_t)l * DM * DI;
        const unsigned char* dwp = dtwP + (size_t)l * 16384;
        const float* cw = conv_w + (size_t)l * DI * 4;
        const float* cb = conv_b + (size_t)l * DI;
        const float* db = dt_b + (size_t)l * DI;
        const float* Dv = Dp + (size_t)l * DI;

        // stage 1: xz = h @ in_proj  (wave w: col-blks w*4..w*4+3; Kp=256 -> 4 groups)
        {
            floatx4 acc[4];
#pragma unroll
            for (int t = 0; t < 4; t++) acc[t] = (floatx4){0.f, 0.f, 0.f, 0.f};
            const unsigned char* Bp = ip + (size_t)(w * 16) * 1024 + lane * 16;
            const unsigned char* Ar = hs + m16 * HB + q * 8;
#pragma unroll
            for (int g = 0; g < 4; g++) {
                long a0 = *(const long*)(Ar + (g * 2) * 32);
                long a1 = *(const long*)(Ar + (g * 2 + 1) * 32);
                long2v b[4];
#pragma unroll
                for (int t = 0; t < 4; t++)
                    b[t] = *(const long2v*)(Bp + (t * 4 + g) * 1024);
#pragma unroll
                for (int t = 0; t < 4; t++)
                    acc[t] = __builtin_amdgcn_mfma_f32_16x16x32_fp8_fp8(a0, b[t].x, acc[t], 0, 0, 0);
#pragma unroll
                for (int t = 0; t < 4; t++)
                    acc[t] = __builtin_amdgcn_mfma_f32_16x16x32_fp8_fp8(a1, b[t].y, acc[t], 0, 0, 0);
            }
            if (w < 8) {
#pragma unroll
                for (int t = 0; t < 4; t++)
#pragma unroll
                    for (int r = 0; r < 4; r++) {
                        int col = w * 64 + t * 16 + m16;
                        float v = silu_f(acc[t][r] * cw[col * 4 + 3] + cb[col]);
                        xcs[(q * 4 + r) * XB + col] = f2fp8(v);
                    }
            } else {
#pragma unroll
                for (int t = 0; t < 4; t++)
#pragma unroll
                    for (int r = 0; r < 4; r++) {
                        int col = (w - 8) * 64 + t * 16 + m16;
                        szs[(q * 4 + r) * XB + col] = f2fp8(silu_f(acc[t][r]));
                    }
            }
        }
        __syncthreads();

        // stage 2: dbl = xc @ x_proj  (waves 0..3: col-blk w; Kp=512 -> 8 groups)
        if (w < 4) {
            floatx4 a0 = (floatx4){0.f, 0.f, 0.f, 0.f};
            floatx4 a1 = (floatx4){0.f, 0.f, 0.f, 0.f};
            const unsigned char* Bp = xp + (size_t)(w * 8) * 1024 + lane * 16;
            const unsigned char* Ar = xcs + m16 * XB + q * 8;
#pragma unroll
            for (int g = 0; g < 8; g++) {
                long2v b = *(const long2v*)(Bp + g * 1024);
                long av0 = *(const long*)(Ar + (g * 2) * 32);
                long av1 = *(const long*)(Ar + (g * 2 + 1) * 32);
                a0 = __builtin_amdgcn_mfma_f32_16x16x32_fp8_fp8(av0, b.x, a0, 0, 0, 0);
                a1 = __builtin_amdgcn_mfma_f32_16x16x32_fp8_fp8(av1, b.y, a1, 0, 0, 0);
            }
            a0 = a0 + a1;
#pragma unroll
            for (int r = 0; r < 4; r++)
                dbls[(q * 4 + r) * 68 + w * 16 + m16] = a0[r];
        }
        __syncthreads();

        // bc[row] = dbl[row,16:32].dbl[row,32:48]
        if (tid < 256) {
            int row = tid >> 4, s = tid & 15;
            float p = dbls[row * 68 + DTR + s] * dbls[row * 68 + DTR + DST + s];
            p += __shfl_xor(p, 1);
            p += __shfl_xor(p, 2);
            p += __shfl_xor(p, 4);
            p += __shfl_xor(p, 8);
            if (s == 0) sbc[row] = p;
        }
        __syncthreads();

        // stage 3 (MFMA): dt = softplus(dbl[:,0:16] @ dtw + db); y = (dt*bc + D)*xc*sz
        // A-frag: A[m=m16][k=q*8+j] from dbls (k>=16 zero); wave w owns cols [w*32, w*32+32)
        {
            long afrag = 0;
            if (q < 2) {
                const float* dr = &dbls[m16 * 68 + q * 8];
                unsigned lo, hi;
                lo = __builtin_amdgcn_cvt_pk_fp8_f32(dr[0], dr[1], 0, false);
                lo = __builtin_amdgcn_cvt_pk_fp8_f32(dr[2], dr[3], lo, true);
                hi = __builtin_amdgcn_cvt_pk_fp8_f32(dr[4], dr[5], 0, false);
                hi = __builtin_amdgcn_cvt_pk_fp8_f32(dr[6], dr[7], hi, true);
                union { unsigned u[2]; long l; } av;
                av.u[0] = lo; av.u[1] = hi;
                afrag = av.l;
            }
            const unsigned char* Wp = dwp + (size_t)(w * 2) * 512 + lane * 8;
            long b0 = *(const long*)(Wp);
            long b1 = *(const long*)(Wp + 512);
            const int c0 = w * 32 + m16, c1 = c0 + 16;
            const float db0 = db[c0], db1 = db[c1];
            floatx4 d0v = (floatx4){db0, db0, db0, db0};
            floatx4 d1v = (floatx4){db1, db1, db1, db1};
            d0v = __builtin_amdgcn_mfma_f32_16x16x32_fp8_fp8(afrag, b0, d0v, 0, 0, 0);
            d1v = __builtin_amdgcn_mfma_f32_16x16x32_fp8_fp8(afrag, b1, d1v, 0, 0, 0);
            const float dv0 = Dv[c0], dv1 = Dv[c1];
#pragma unroll
            for (int r = 0; r < 4; r++) {
                int row = q * 4 + r;
                float bcv = sbc[row];
                int off0 = row * XB + c0;
                float v0 = (softplus_f(d0v[r]) * bcv + dv0) * fp82f(xcs[off0]) * fp82f(szs[off0]);
                xcs[off0] = f2fp8(v0);
                int off1 = off0 + 16;
                float v1 = (softplus_f(d1v[r]) * bcv + dv1) * fp82f(xcs[off1]) * fp82f(szs[off1]);
                xcs[off1] = f2fp8(v1);
            }
        }
        __syncthreads();

        // stage 4: h = y @ out_proj  (wave w: col-blk w; Kp=512 -> 8 groups)
        {
            floatx4 a0 = (floatx4){0.f, 0.f, 0.f, 0.f};
            floatx4 a1 = (floatx4){0.f, 0.f, 0.f, 0.f};
            const unsigned char* Bp = op + (size_t)(w * 8) * 1024 + lane * 16;
            const unsigned char* Ar = xcs + m16 * XB + q * 8;
#pragma unroll
            for (int g = 0; g < 8; g++) {
                long2v b = *(const long2v*)(Bp + g * 1024);
                long av0 = *(const long*)(Ar + (g * 2) * 32);
                long av1 = *(const long*)(Ar + (g * 2 + 1) * 32);
                a0 = __builtin_amdgcn_mfma_f32_16x16x32_fp8_fp8(av0, b.x, a0, 0, 0, 0);
                a1 = __builtin_amdgcn_mfma_f32_16x16x32_fp8_fp8(av1, b.y, a1, 0, 0, 0);
            }
            a0 = a0 + a1;
            int col = w * 16 + m16;
#pragma unroll
            for (int r = 0; r < 4; r++)
                hs[(q * 4 + r) * HB + col] = f2fp8(a0[r]);
        }
        __syncthreads();
    }

    // final: wave w reduces row w
    {
        float s = 0.0f;
#pragma unroll
        for (int j = 0; j < 4; j++)
            s += fp82f(hs[w * HB + lane * 4 + j]) * Wo[lane * 4 + j];
#pragma unroll
        for (int off = 32; off > 0; off >>= 1) s += __shfl_down(s, off);
        if (lane == 0) out[rb + w] = s + bo[0];
    }
}

extern "C" void kernel_launch(void* const* d_in, const int* in_sizes, int n_in,
                              void* d_out, int out_size, void* d_ws, size_t ws_size,
                              hipStream_t stream)
{
    const float* x       = (const float*)d_in[0];
    const float* Wi      = (const float*)d_in[1];
    const float* bi      = (const float*)d_in[2];
    const float* in_proj = (const float*)d_in[3];
    const float* conv_w  = (const float*)d_in[4];
    const float* conv_b  = (const float*)d_in[5];
    const float* x_proj  = (const float*)d_in[6];
    const float* dt_w    = (const float*)d_in[7];
    const float* dt_b    = (const float*)d_in[8];
    // d_in[9] = A_log: dead (L==1, h0==0)
    const float* Dp      = (const float*)d_in[10];
    const float* out_pw  = (const float*)d_in[11];
    const float* Wo      = (const float*)d_in[12];
    const float* bo      = (const float*)d_in[13];

    unsigned char* ws = (unsigned char*)d_ws;
    unsigned char* xpad = ws;                              // 4096*256
    unsigned char* WiT  = xpad + (size_t)NB * DM;          // 256*256
    unsigned char* ipT  = WiT + (size_t)DM * DM;           // 12*1024*256
    unsigned char* opT  = ipT + (size_t)NL * 2 * DI * DM;  // 12*256*512
    unsigned char* xpT  = opT + (size_t)NL * DM * DI;      // 12*64*512
    unsigned char* dtwP = xpT + (size_t)NL * 64 * DI;      // 12*16384 fp8 fragments

    dim3 blk(256);

    conv_x<<<dim3(NB * DM / 256), blk, 0, stream>>>(x, xpad);
    conv_wt_pack<<<dim3(DM * DM / 256, 1), blk, 0, stream>>>(Wi, WiT, IN_D, DM, DM, DM);
    conv_wt_pack<<<dim3(2 * DI * DM / 256, NL), blk, 0, stream>>>(in_proj, ipT, DM, 2 * DI, DM, 2 * DI);
    conv_wt_pack<<<dim3(DM * DI / 256, NL), blk, 0, stream>>>(out_pw, opT, DI, DM, DI, DM);
    conv_wt_pack<<<dim3(64 * DI / 256, NL), blk, 0, stream>>>(x_proj, xpT, DI, XPN, DI, 64);
    conv_dtw_pack<<<dim3(64, NL), blk, 0, stream>>>(dt_w, dtwP);

    mamba_all<<<dim3(NB / 16), dim3(1024), 0, stream>>>(
        xpad, WiT, bi, ipT, opT, xpT, dtwP,
        conv_w, conv_b, dt_b, Dp, Wo, bo, (float*)d_out);
}